// Round 11
// baseline (904.483 us; speedup 1.0000x reference)
//
#include <hip/hip_runtime.h>
#include <hip/hip_bf16.h>

#define B_   8
#define C_   512
#define N_   4096
#define G_   32
#define CPG  16
#define EPSV 1e-6f

typedef short s16x8 __attribute__((ext_vector_type(8)));
typedef float f32x4 __attribute__((ext_vector_type(4)));

__device__ __forceinline__ unsigned short f2bf(float f) {
    unsigned u = __builtin_bit_cast(unsigned, f);
    u += 0x7fffu + ((u >> 16) & 1u);
    return (unsigned short)(u >> 16);
}

__device__ __forceinline__ void gload_lds16(const unsigned short* g, unsigned short* l) {
    __builtin_amdgcn_global_load_lds((const __attribute__((address_space(1))) void*)g,
                                     (__attribute__((address_space(3))) void*)l, 16, 0, 0);
}

// ---------------------------------------------------------------- kernel 1
__global__ __launch_bounds__(256) void gn_stats_k(const float* __restrict__ x,
                                                  float* __restrict__ stats) {
    int blk = blockIdx.x;  // b*32+g
    const float4* p = (const float4*)(x + (size_t)blk * (CPG * N_));
    float s = 0.f, ss = 0.f;
    for (int i = threadIdx.x; i < (CPG * N_) / 4; i += 256) {
        float4 v = p[i];
        s  += v.x + v.y + v.z + v.w;
        ss += v.x * v.x + v.y * v.y + v.z * v.z + v.w * v.w;
    }
    for (int off = 32; off > 0; off >>= 1) {
        s  += __shfl_down(s, off);
        ss += __shfl_down(ss, off);
    }
    __shared__ float r0[4], r1[4];
    int wid = threadIdx.x >> 6;
    if ((threadIdx.x & 63) == 0) { r0[wid] = s; r1[wid] = ss; }
    __syncthreads();
    if (threadIdx.x == 0) {
        s  = r0[0] + r0[1] + r0[2] + r0[3];
        ss = r1[0] + r1[1] + r1[2] + r1[3];
        const float inv = 1.0f / (CPG * N_);
        float mean = s * inv;
        float var  = ss * inv - mean * mean;
        stats[2 * blk]     = mean;
        stats[2 * blk + 1] = rsqrtf(var + EPSV);
    }
}

// ---------------------------------------------------------------- kernel 2
__global__ __launch_bounds__(256) void cvt_w_k(const float* __restrict__ wq,
                                               const float* __restrict__ wk,
                                               const float* __restrict__ wv,
                                               unsigned short* __restrict__ wbf) {
    int i = blockIdx.x * 256 + threadIdx.x;
    const int percc = C_ * C_ / 4;
    const float* src; int li;
    if (i < percc)            { src = wq; li = i; }
    else if (i < 2 * percc)   { src = wk; li = i - percc; }
    else                      { src = wv; li = i - 2 * percc; }
    float4 v = ((const float4*)src)[li];
    unsigned u0 = (unsigned)f2bf(v.x) | ((unsigned)f2bf(v.y) << 16);
    unsigned u1 = (unsigned)f2bf(v.z) | ((unsigned)f2bf(v.w) << 16);
    uint2 o; o.x = u0; o.y = u1;
    *(uint2*)&wbf[(size_t)i * 4] = o;
}

// ---------------------------------------------------------------- kernel 3
__global__ __launch_bounds__(256) void gn_apply_k(const float* __restrict__ x,
                                                  const float* __restrict__ stats,
                                                  const float* __restrict__ gsc,
                                                  const float* __restrict__ gbi,
                                                  unsigned short* __restrict__ h_t) {
    int nt = blockIdx.x, ct = blockIdx.y, b = blockIdx.z;
    int n0 = nt * 64, c0 = ct * 64;
    __shared__ unsigned short T[64][72];
    int t = threadIdx.x;
    int cl = t >> 2, ch = t & 3;
    int c = c0 + cl;
    int g = c >> 4;
    float mean = stats[(b * G_ + g) * 2];
    float rstd = stats[(b * G_ + g) * 2 + 1];
    float sc = gsc[c] * rstd;
    float bi = gbi[c] - mean * sc;
    const float* xr = x + (size_t)(b * C_ + c) * N_ + n0 + ch * 16;
    #pragma unroll
    for (int q = 0; q < 4; ++q) {
        float4 v = *(const float4*)(xr + q * 4);
        int nl = ch * 16 + q * 4;
        T[nl + 0][cl] = f2bf(fmaf(v.x, sc, bi));
        T[nl + 1][cl] = f2bf(fmaf(v.y, sc, bi));
        T[nl + 2][cl] = f2bf(fmaf(v.z, sc, bi));
        T[nl + 3][cl] = f2bf(fmaf(v.w, sc, bi));
    }
    __syncthreads();
    #pragma unroll
    for (int it = 0; it < 2; ++it) {
        int id = t + it * 256;
        int nl = id >> 3, part = id & 7;
        s16x8 val = *(const s16x8*)&T[nl][part * 8];
        *(s16x8*)&h_t[((size_t)b * N_ + n0 + nl) * C_ + c0 + part * 8] = val;
    }
}

// ---------------------------------------------------------------- kernel 3b
__global__ __launch_bounds__(256) void copyx_k(const float* __restrict__ x,
                                               float* __restrict__ out) {
    const size_t total4 = (size_t)B_ * C_ * N_ / 4;
    size_t stride = (size_t)gridDim.x * 256;
    for (size_t i = blockIdx.x * 256 + threadIdx.x; i < total4; i += stride)
        ((float4*)out)[i] = ((const float4*)x)[i];
}

// ---------------------------------------------------------------- 128^2 2-phase core (qkv)
__device__ __forceinline__ void gemm_core(const unsigned short* A, int ldA,
                                          const unsigned short* Bm, int ldB,
                                          unsigned short* Al, unsigned short* Bl,
                                          f32x4 (&acc)[4][4], int ksteps, int t) {
    int w = t >> 6, l = t & 63;
    int wm = (w >> 1) * 64, wn = (w & 1) * 64;
    int lr = l & 15, lg = l >> 4;
    int srow = w * 16 + (l >> 2);
    int sp   = (l & 3) * 8;

    #pragma unroll
    for (int it = 0; it < 2; ++it) {
        gload_lds16(&A [(size_t)(it * 64 + srow) * ldA + sp], &Al[it * 2048 + w * 512 + l * 8]);
        gload_lds16(&Bm[(size_t)(it * 64 + srow) * ldB + sp], &Bl[it * 2048 + w * 512 + l * 8]);
    }
    __syncthreads();

    int cur = 0;
    for (int s = 0; s < ksteps; ++s) {
        if (s + 1 < ksteps) {
            const unsigned short* ga = A  + (s + 1) * 32;
            const unsigned short* gb = Bm + (s + 1) * 32;
            int off = (cur ^ 1) * 4096;
            #pragma unroll
            for (int it = 0; it < 2; ++it) {
                gload_lds16(&ga[(size_t)(it * 64 + srow) * ldA + sp], &Al[off + it * 2048 + w * 512 + l * 8]);
                gload_lds16(&gb[(size_t)(it * 64 + srow) * ldB + sp], &Bl[off + it * 2048 + w * 512 + l * 8]);
            }
        }
        const unsigned short* la = Al + cur * 4096;
        const unsigned short* lb = Bl + cur * 4096;
        s16x8 a[4], b[4];
        #pragma unroll
        for (int i = 0; i < 4; ++i) a[i] = *(const s16x8*)&la[(wm + i * 16 + lr) * 32 + lg * 8];
        #pragma unroll
        for (int j = 0; j < 4; ++j) b[j] = *(const s16x8*)&lb[(wn + j * 16 + lr) * 32 + lg * 8];
        #pragma unroll
        for (int i = 0; i < 4; ++i)
            #pragma unroll
            for (int j = 0; j < 4; ++j)
                acc[i][j] = __builtin_amdgcn_mfma_f32_16x16x32_bf16(a[i], b[j], acc[i][j], 0, 0, 0);
        __syncthreads();
        cur ^= 1;
    }
}

// ---------------------------------------------------------------- kernel 4: QKV projections
__global__ __launch_bounds__(256, 4) void qkv_k(const unsigned short* __restrict__ h_t,
                                                const unsigned short* __restrict__ wbf,
                                                const float* __restrict__ bq,
                                                const float* __restrict__ bk,
                                                const float* __restrict__ bv,
                                                unsigned short* __restrict__ q_t,
                                                unsigned short* __restrict__ k_t,
                                                unsigned short* __restrict__ vv) {
    int which = blockIdx.z % 3;
    int b     = blockIdx.z / 3;
    int bx = blockIdx.x, by = blockIdx.y;
    const unsigned short* A;
    const unsigned short* Bm;
    unsigned short* Cm;
    const float* bias;
    int m0, n0; size_t ldc; bool biasRow;
    const unsigned short* hb = h_t + (size_t)b * N_ * C_;
    if (which < 2) {
        A = hb; Bm = wbf + (size_t)which * C_ * C_;
        Cm = (which == 0 ? q_t : k_t) + (size_t)b * N_ * C_;
        bias = (which == 0 ? bq : bk);
        m0 = bx * 128; n0 = by * 128; ldc = C_; biasRow = false;
    } else {
        A = wbf + (size_t)2 * C_ * C_; Bm = hb;
        Cm = vv + (size_t)b * C_ * N_;
        bias = bv;
        m0 = by * 128; n0 = bx * 128; ldc = N_; biasRow = true;
    }

    __shared__ char smem[35072];
    unsigned short* Al = (unsigned short*)smem;
    unsigned short* Bl = Al + 8192;
    unsigned short* El = (unsigned short*)smem;

    int t = threadIdx.x;
    int wid = t >> 6, lane = t & 63;
    int wm = (wid >> 1) * 64, wn = (wid & 1) * 64;
    int lr = lane & 15, lg = lane >> 4;

    f32x4 acc[4][4] = {};
    gemm_core(A + (size_t)m0 * C_, C_, Bm + (size_t)n0 * C_, C_, Al, Bl, acc, C_ / 32, t);

    float rb[4][4], cb[4];
    #pragma unroll
    for (int i = 0; i < 4; ++i)
        #pragma unroll
        for (int r = 0; r < 4; ++r)
            rb[i][r] = biasRow ? bias[m0 + wm + i * 16 + lg * 4 + r] : 0.f;
    #pragma unroll
    for (int j = 0; j < 4; ++j)
        cb[j] = biasRow ? 0.f : bias[n0 + wn + j * 16 + lr];

    #pragma unroll
    for (int i = 0; i < 4; ++i)
        #pragma unroll
        for (int j = 0; j < 4; ++j) {
            int col = wn + j * 16 + lr;
            #pragma unroll
            for (int r = 0; r < 4; ++r) {
                int row = wm + i * 16 + lg * 4 + r;
                El[row * 136 + col] = f2bf(acc[i][j][r] + rb[i][r] + cb[j]);
            }
        }
    __syncthreads();
    #pragma unroll
    for (int it = 0; it < 8; ++it) {
        int id = t + it * 256;
        int row = id >> 4, part = id & 15;
        *(s16x8*)&Cm[(size_t)(m0 + row) * ldc + n0 + part * 8] =
            *(const s16x8*)&El[row * 136 + part * 8];
    }
}

// ---------------------------------------------------------------- kernel 5
__global__ __launch_bounds__(512) void zeroL_k(float* __restrict__ L) {
    L[blockIdx.x * 512 + threadIdx.x] = 0.f;
}

// ================================================================ 256^2 core, BK=32, staging < 64 KB
// A dbuf: 2 x [256][32] bf16 = 32 KB at bytes [0, 32768).
// B dbuf: 32 KB at bytes [32768, 65536).
// XOR swizzle over 4 16B-slots/row, both-sides (rule #21).
// Per K-tile: STAGE(t+1) -> ds_read(t) -> 32 MFMA/wave -> __syncthreads().
__device__ __forceinline__ void stage256b(const unsigned short* g, int ldg,
                                          unsigned short* dst, int tid) {
    int r0 = tid >> 2, c = tid & 3;
    #pragma unroll
    for (int i = 0; i < 2; ++i) {
        int row = r0 + i * 128;
        int cs = c ^ (row & 3);
        gload_lds16(&g[(size_t)row * ldg + cs * 8], &dst[row * 32 + c * 8]);
    }
}

__device__ __forceinline__ void gemm256_core(const unsigned short* A, int ldA,
                                             const unsigned short* Bm, int ldB,
                                             unsigned short* sm, int nt,
                                             f32x4 (&acc)[8][4]) {
    const int tid = threadIdx.x;
    const int w = tid >> 6, l = tid & 63;
    const int lr = l & 15, lg = l >> 4;
    const int wm = (w >> 2) * 128, wn = (w & 3) * 64;
    unsigned short* Asm = sm;               // [2][256*32] shorts, bytes [0,32768)
    unsigned short* Bsm = sm + 2 * 8192;    // bytes [32768,65536)

    stage256b(A, ldA, Asm, tid);
    stage256b(Bm, ldB, Bsm, tid);
    __syncthreads();

    for (int t = 0; t < nt; ++t) {
        const int cur = (t & 1) * 8192;
        if (t + 1 < nt) {
            const int nxt = ((t + 1) & 1) * 8192;
            stage256b(A  + (size_t)(t + 1) * 32, ldA, Asm + nxt, tid);
            stage256b(Bm + (size_t)(t + 1) * 32, ldB, Bsm + nxt, tid);
        }
        s16x8 av[8], bv[4];
        #pragma unroll
        for (int i = 0; i < 8; ++i) {
            int row = wm + i * 16 + lr;
            av[i] = *(const s16x8*)&Asm[cur + row * 32 + ((lg ^ (row & 3)) * 8)];
        }
        #pragma unroll
        for (int j = 0; j < 4; ++j) {
            int row = wn + j * 16 + lr;
            bv[j] = *(const s16x8*)&Bsm[cur + row * 32 + ((lg ^ (row & 3)) * 8)];
        }
        #pragma unroll
        for (int i = 0; i < 8; ++i)
            #pragma unroll
            for (int j = 0; j < 4; ++j)
                acc[i][j] = __builtin_amdgcn_mfma_f32_16x16x32_bf16(av[i], bv[j], acc[i][j], 0, 0, 0);
        __syncthreads();
    }
}

// ---------------------------------------------------------------- kernel 6: S-GEMM 256^2
// El is [256][256] shorts = exactly 128 KB (stride 256 — R7-R10 used 136, which
// CLOBBERED cols >=136 of every row into the next row: the ~0.22 absmax bug).
__global__ __launch_bounds__(512) void sgemm256_k(const unsigned short* __restrict__ q_t,
                                                  const unsigned short* __restrict__ k_t,
                                                  unsigned short* __restrict__ Ptil,
                                                  float* __restrict__ L,
                                                  int bbase) {
    __shared__ char smem[131072];
    int z = blockIdx.z;
    int b = bbase + z;
    int m0 = blockIdx.y * 256, n0 = blockIdx.x * 256;
    const unsigned short* A  = q_t + (size_t)b * N_ * C_ + (size_t)m0 * C_;
    const unsigned short* Bm = k_t + (size_t)b * N_ * C_ + (size_t)n0 * C_;

    f32x4 acc[8][4] = {};
    gemm256_core(A, C_, Bm, C_, (unsigned short*)smem, C_ / 32, acc);

    const int tid = threadIdx.x;
    const int w = tid >> 6, l = tid & 63;
    const int lr = l & 15, lg = l >> 4;
    const int wm = (w >> 2) * 128, wn = (w & 3) * 64;
    const float SCL2 = 0.06375862f;  // log2(e)/sqrt(512)

    unsigned short* El = (unsigned short*)smem;  // [256][256] = 128 KB exactly
    float rsum[8][4];
    #pragma unroll
    for (int i = 0; i < 8; ++i)
        #pragma unroll
        for (int r = 0; r < 4; ++r) rsum[i][r] = 0.f;

    #pragma unroll
    for (int i = 0; i < 8; ++i)
        #pragma unroll
        for (int j = 0; j < 4; ++j) {
            int col = wn + j * 16 + lr;
            #pragma unroll
            for (int r = 0; r < 4; ++r) {
                float p = exp2f(acc[i][j][r] * SCL2);
                rsum[i][r] += p;
                El[(wm + i * 16 + lg * 4 + r) * 256 + col] = f2bf(p);
            }
        }
    #pragma unroll
    for (int msk = 8; msk >= 1; msk >>= 1)
        #pragma unroll
        for (int i = 0; i < 8; ++i)
            #pragma unroll
            for (int r = 0; r < 4; ++r)
                rsum[i][r] += __shfl_xor(rsum[i][r], msk);
    if (lr == 0) {
        #pragma unroll
        for (int i = 0; i < 8; ++i)
            #pragma unroll
            for (int r = 0; r < 4; ++r)
                atomicAdd(&L[(size_t)b * N_ + m0 + wm + i * 16 + lg * 4 + r], rsum[i][r]);
    }
    __syncthreads();
    unsigned short* Cm = Ptil + (size_t)z * N_ * N_;
    #pragma unroll
    for (int it = 0; it < 16; ++it) {
        int u = tid + it * 512;
        int row = u >> 5, part = u & 31;
        *(s16x8*)&Cm[(size_t)(m0 + row) * N_ + n0 + part * 8] =
            *(const s16x8*)&El[row * 256 + part * 8];
    }
}

// ---------------------------------------------------------------- kernel 7: PV 256^2 (atomic; out preset to x)
__global__ __launch_bounds__(512) void pv256_k(const unsigned short* __restrict__ vv,
                                               const unsigned short* __restrict__ Ptil,
                                               const float* __restrict__ L,
                                               float* __restrict__ out,
                                               int bbase, int SK) {
    __shared__ char smem[65536];
    int z = blockIdx.z;
    int slot = z / SK, kr = z % SK;
    int b = bbase + slot;
    int kOff = kr * (N_ / SK);
    int m0 = blockIdx.y * 256, n0 = blockIdx.x * 256;
    const unsigned short* A  = vv   + (size_t)b * C_ * N_ + (size_t)m0 * N_ + kOff;
    const unsigned short* Bm = Ptil + (size_t)slot * N_ * N_ + (size_t)n0 * N_ + kOff;
    float* ob = out + (size_t)b * C_ * N_;

    f32x4 acc[8][4] = {};
    gemm256_core(A, N_, Bm, N_, (unsigned short*)smem, (N_ / SK) / 32, acc);

    const int tid = threadIdx.x;
    const int w = tid >> 6, l = tid & 63;
    const int lr = l & 15, lg = l >> 4;
    const int wm = (w >> 2) * 128, wn = (w & 3) * 64;

    #pragma unroll
    for (int j = 0; j < 4; ++j) {
        int col = n0 + wn + j * 16 + lr;
        float rl = 1.0f / L[(size_t)b * N_ + col];
        #pragma unroll
        for (int i = 0; i < 8; ++i) {
            #pragma unroll
            for (int r = 0; r < 4; ++r) {
                int row = m0 + wm + i * 16 + lg * 4 + r;
                atomicAdd(&ob[(size_t)row * N_ + col], acc[i][j][r] * rl);
            }
        }
    }
}

// ---------------------------------------------------------------- launch
extern "C" void kernel_launch(void* const* d_in, const int* in_sizes, int n_in,
                              void* d_out, int out_size, void* d_ws, size_t ws_size,
                              hipStream_t stream) {
    const float* x   = (const float*)d_in[0];
    const float* gsc = (const float*)d_in[1];
    const float* gbi = (const float*)d_in[2];
    const float* wq  = (const float*)d_in[3];
    const float* bq  = (const float*)d_in[4];
    const float* wk  = (const float*)d_in[5];
    const float* bk  = (const float*)d_in[6];
    const float* wv  = (const float*)d_in[7];
    const float* bv  = (const float*)d_in[8];
    float* out = (float*)d_out;

    const size_t elems = (size_t)B_ * N_ * C_;   // 16.7M
    unsigned short* q_t   = (unsigned short*)d_ws;
    unsigned short* k_t   = q_t + elems;
    unsigned short* v     = k_t + elems;
    float*          stats = (float*)(v + elems);
    unsigned short* wbf   = (unsigned short*)(stats + 2 * B_ * G_);
    float*          L     = (float*)(wbf + (size_t)3 * C_ * C_);
    unsigned short* Ptil  = (unsigned short*)(L + (size_t)B_ * N_);
    unsigned short* h_t   = (unsigned short*)d_out;  // dead after qkv_k

    const size_t base_bytes = (size_t)((char*)Ptil - (char*)d_ws);
    const size_t slot_bytes = (size_t)N_ * N_ * 2;
    int slots = 2;
    if      (ws_size >= base_bytes + 8 * slot_bytes) slots = 8;
    else if (ws_size >= base_bytes + 4 * slot_bytes) slots = 4;
    const int SK = 32 / slots;   // pv z-dim = slots*SK = 32 always (1024 blocks)

    gn_stats_k<<<B_ * G_, 256, 0, stream>>>(x, stats);
    cvt_w_k<<<(3 * C_ * C_ / 4) / 256, 256, 0, stream>>>(wq, wk, wv, wbf);
    gn_apply_k<<<dim3(N_ / 64, C_ / 64, B_), 256, 0, stream>>>(x, stats, gsc, gbi, h_t);
    qkv_k<<<dim3(32, 4, 3 * B_), 256, 0, stream>>>(h_t, wbf, bq, bk, bv, q_t, k_t, v);
    zeroL_k<<<(B_ * N_) / 512, 512, 0, stream>>>(L);
    copyx_k<<<2048, 256, 0, stream>>>(x, out);   // out = x; pv atomically adds

    for (int bb = 0; bb < B_; bb += slots) {
        sgemm256_k<<<dim3(16, 16, slots), 512, 0, stream>>>(q_t, k_t, Ptil, L, bb);
        pv256_k<<<dim3(16, 2, 32), 512, 0, stream>>>(v, Ptil, L, out, bb, SK);
    }
}

// Round 12
// 682.456 us; speedup vs baseline: 1.3253x; 1.3253x over previous
//
#include <hip/hip_runtime.h>
#include <hip/hip_bf16.h>

#define B_   8
#define C_   512
#define N_   4096
#define G_   32
#define CPG  16
#define EPSV 1e-6f

typedef short s16x8 __attribute__((ext_vector_type(8)));
typedef float f32x4 __attribute__((ext_vector_type(4)));

__device__ __forceinline__ unsigned short f2bf(float f) {
    unsigned u = __builtin_bit_cast(unsigned, f);
    u += 0x7fffu + ((u >> 16) & 1u);
    return (unsigned short)(u >> 16);
}

__device__ __forceinline__ void gload_lds16(const unsigned short* g, unsigned short* l) {
    __builtin_amdgcn_global_load_lds((const __attribute__((address_space(1))) void*)g,
                                     (__attribute__((address_space(3))) void*)l, 16, 0, 0);
}

// ---------------------------------------------------------------- kernel 1
__global__ __launch_bounds__(256) void gn_stats_k(const float* __restrict__ x,
                                                  float* __restrict__ stats) {
    int blk = blockIdx.x;  // b*32+g
    const float4* p = (const float4*)(x + (size_t)blk * (CPG * N_));
    float s = 0.f, ss = 0.f;
    for (int i = threadIdx.x; i < (CPG * N_) / 4; i += 256) {
        float4 v = p[i];
        s  += v.x + v.y + v.z + v.w;
        ss += v.x * v.x + v.y * v.y + v.z * v.z + v.w * v.w;
    }
    for (int off = 32; off > 0; off >>= 1) {
        s  += __shfl_down(s, off);
        ss += __shfl_down(ss, off);
    }
    __shared__ float r0[4], r1[4];
    int wid = threadIdx.x >> 6;
    if ((threadIdx.x & 63) == 0) { r0[wid] = s; r1[wid] = ss; }
    __syncthreads();
    if (threadIdx.x == 0) {
        s  = r0[0] + r0[1] + r0[2] + r0[3];
        ss = r1[0] + r1[1] + r1[2] + r1[3];
        const float inv = 1.0f / (CPG * N_);
        float mean = s * inv;
        float var  = ss * inv - mean * mean;
        stats[2 * blk]     = mean;
        stats[2 * blk + 1] = rsqrtf(var + EPSV);
    }
}

// ---------------------------------------------------------------- kernel 2
__global__ __launch_bounds__(256) void cvt_w_k(const float* __restrict__ wq,
                                               const float* __restrict__ wk,
                                               const float* __restrict__ wv,
                                               unsigned short* __restrict__ wbf) {
    int i = blockIdx.x * 256 + threadIdx.x;
    const int percc = C_ * C_ / 4;
    const float* src; int li;
    if (i < percc)            { src = wq; li = i; }
    else if (i < 2 * percc)   { src = wk; li = i - percc; }
    else                      { src = wv; li = i - 2 * percc; }
    float4 v = ((const float4*)src)[li];
    unsigned u0 = (unsigned)f2bf(v.x) | ((unsigned)f2bf(v.y) << 16);
    unsigned u1 = (unsigned)f2bf(v.z) | ((unsigned)f2bf(v.w) << 16);
    uint2 o; o.x = u0; o.y = u1;
    *(uint2*)&wbf[(size_t)i * 4] = o;
}

// ---------------------------------------------------------------- kernel 3
__global__ __launch_bounds__(256) void gn_apply_k(const float* __restrict__ x,
                                                  const float* __restrict__ stats,
                                                  const float* __restrict__ gsc,
                                                  const float* __restrict__ gbi,
                                                  unsigned short* __restrict__ h_t) {
    int nt = blockIdx.x, ct = blockIdx.y, b = blockIdx.z;
    int n0 = nt * 64, c0 = ct * 64;
    __shared__ unsigned short T[64][72];
    int t = threadIdx.x;
    int cl = t >> 2, ch = t & 3;
    int c = c0 + cl;
    int g = c >> 4;
    float mean = stats[(b * G_ + g) * 2];
    float rstd = stats[(b * G_ + g) * 2 + 1];
    float sc = gsc[c] * rstd;
    float bi = gbi[c] - mean * sc;
    const float* xr = x + (size_t)(b * C_ + c) * N_ + n0 + ch * 16;
    #pragma unroll
    for (int q = 0; q < 4; ++q) {
        float4 v = *(const float4*)(xr + q * 4);
        int nl = ch * 16 + q * 4;
        T[nl + 0][cl] = f2bf(fmaf(v.x, sc, bi));
        T[nl + 1][cl] = f2bf(fmaf(v.y, sc, bi));
        T[nl + 2][cl] = f2bf(fmaf(v.z, sc, bi));
        T[nl + 3][cl] = f2bf(fmaf(v.w, sc, bi));
    }
    __syncthreads();
    #pragma unroll
    for (int it = 0; it < 2; ++it) {
        int id = t + it * 256;
        int nl = id >> 3, part = id & 7;
        s16x8 val = *(const s16x8*)&T[nl][part * 8];
        *(s16x8*)&h_t[((size_t)b * N_ + n0 + nl) * C_ + c0 + part * 8] = val;
    }
}

// ---------------------------------------------------------------- kernel 3b
__global__ __launch_bounds__(256) void copyx_k(const float* __restrict__ x,
                                               float* __restrict__ out) {
    const size_t total4 = (size_t)B_ * C_ * N_ / 4;
    size_t stride = (size_t)gridDim.x * 256;
    for (size_t i = blockIdx.x * 256 + threadIdx.x; i < total4; i += stride)
        ((float4*)out)[i] = ((const float4*)x)[i];
}

// ---------------------------------------------------------------- 128^2 2-phase core
__device__ __forceinline__ void gemm_core(const unsigned short* A, int ldA,
                                          const unsigned short* Bm, int ldB,
                                          unsigned short* Al, unsigned short* Bl,
                                          f32x4 (&acc)[4][4], int ksteps, int t) {
    int w = t >> 6, l = t & 63;
    int wm = (w >> 1) * 64, wn = (w & 1) * 64;
    int lr = l & 15, lg = l >> 4;
    int srow = w * 16 + (l >> 2);
    int sp   = (l & 3) * 8;

    #pragma unroll
    for (int it = 0; it < 2; ++it) {
        gload_lds16(&A [(size_t)(it * 64 + srow) * ldA + sp], &Al[it * 2048 + w * 512 + l * 8]);
        gload_lds16(&Bm[(size_t)(it * 64 + srow) * ldB + sp], &Bl[it * 2048 + w * 512 + l * 8]);
    }
    __syncthreads();

    int cur = 0;
    for (int s = 0; s < ksteps; ++s) {
        if (s + 1 < ksteps) {
            const unsigned short* ga = A  + (s + 1) * 32;
            const unsigned short* gb = Bm + (s + 1) * 32;
            int off = (cur ^ 1) * 4096;
            #pragma unroll
            for (int it = 0; it < 2; ++it) {
                gload_lds16(&ga[(size_t)(it * 64 + srow) * ldA + sp], &Al[off + it * 2048 + w * 512 + l * 8]);
                gload_lds16(&gb[(size_t)(it * 64 + srow) * ldB + sp], &Bl[off + it * 2048 + w * 512 + l * 8]);
            }
        }
        const unsigned short* la = Al + cur * 4096;
        const unsigned short* lb = Bl + cur * 4096;
        s16x8 a[4], b[4];
        #pragma unroll
        for (int i = 0; i < 4; ++i) a[i] = *(const s16x8*)&la[(wm + i * 16 + lr) * 32 + lg * 8];
        #pragma unroll
        for (int j = 0; j < 4; ++j) b[j] = *(const s16x8*)&lb[(wn + j * 16 + lr) * 32 + lg * 8];
        #pragma unroll
        for (int i = 0; i < 4; ++i)
            #pragma unroll
            for (int j = 0; j < 4; ++j)
                acc[i][j] = __builtin_amdgcn_mfma_f32_16x16x32_bf16(a[i], b[j], acc[i][j], 0, 0, 0);
        __syncthreads();
        cur ^= 1;
    }
}

// ---------------------------------------------------------------- kernel 4: QKV projections
__global__ __launch_bounds__(256, 4) void qkv_k(const unsigned short* __restrict__ h_t,
                                                const unsigned short* __restrict__ wbf,
                                                const float* __restrict__ bq,
                                                const float* __restrict__ bk,
                                                const float* __restrict__ bv,
                                                unsigned short* __restrict__ q_t,
                                                unsigned short* __restrict__ k_t,
                                                unsigned short* __restrict__ vv) {
    int which = blockIdx.z % 3;
    int b     = blockIdx.z / 3;
    int bx = blockIdx.x, by = blockIdx.y;
    const unsigned short* A;
    const unsigned short* Bm;
    unsigned short* Cm;
    const float* bias;
    int m0, n0; size_t ldc; bool biasRow;
    const unsigned short* hb = h_t + (size_t)b * N_ * C_;
    if (which < 2) {
        A = hb; Bm = wbf + (size_t)which * C_ * C_;
        Cm = (which == 0 ? q_t : k_t) + (size_t)b * N_ * C_;
        bias = (which == 0 ? bq : bk);
        m0 = bx * 128; n0 = by * 128; ldc = C_; biasRow = false;
    } else {
        A = wbf + (size_t)2 * C_ * C_; Bm = hb;
        Cm = vv + (size_t)b * C_ * N_;
        bias = bv;
        m0 = by * 128; n0 = bx * 128; ldc = N_; biasRow = true;
    }

    __shared__ char smem[35072];
    unsigned short* Al = (unsigned short*)smem;
    unsigned short* Bl = Al + 8192;
    unsigned short* El = (unsigned short*)smem;

    int t = threadIdx.x;
    int wid = t >> 6, lane = t & 63;
    int wm = (wid >> 1) * 64, wn = (wid & 1) * 64;
    int lr = lane & 15, lg = lane >> 4;

    f32x4 acc[4][4] = {};
    gemm_core(A + (size_t)m0 * C_, C_, Bm + (size_t)n0 * C_, C_, Al, Bl, acc, C_ / 32, t);

    float rb[4][4], cb[4];
    #pragma unroll
    for (int i = 0; i < 4; ++i)
        #pragma unroll
        for (int r = 0; r < 4; ++r)
            rb[i][r] = biasRow ? bias[m0 + wm + i * 16 + lg * 4 + r] : 0.f;
    #pragma unroll
    for (int j = 0; j < 4; ++j)
        cb[j] = biasRow ? 0.f : bias[n0 + wn + j * 16 + lr];

    #pragma unroll
    for (int i = 0; i < 4; ++i)
        #pragma unroll
        for (int j = 0; j < 4; ++j) {
            int col = wn + j * 16 + lr;
            #pragma unroll
            for (int r = 0; r < 4; ++r) {
                int row = wm + i * 16 + lg * 4 + r;
                El[row * 136 + col] = f2bf(acc[i][j][r] + rb[i][r] + cb[j]);
            }
        }
    __syncthreads();
    #pragma unroll
    for (int it = 0; it < 8; ++it) {
        int id = t + it * 256;
        int row = id >> 4, part = id & 15;
        *(s16x8*)&Cm[(size_t)(m0 + row) * ldc + n0 + part * 8] =
            *(const s16x8*)&El[row * 136 + part * 8];
    }
}

// ---------------------------------------------------------------- kernel 5
__global__ __launch_bounds__(512) void zeroL_k(float* __restrict__ L) {
    L[blockIdx.x * 512 + threadIdx.x] = 0.f;
}

// ================================================================ 256^2 core, BK=32, staging 64 KB
// A dbuf: 2 x [256][32] bf16 = 32 KB at [0,32K); B dbuf at [32K,64K).
// XOR swizzle over 4 16B-slots/row, both-sides. Per K-tile:
// STAGE(t+1) -> ds_read(t) -> 32 MFMA/wave -> __syncthreads().  (proven R11)
__device__ __forceinline__ void stage256b(const unsigned short* g, int ldg,
                                          unsigned short* dst, int tid) {
    int r0 = tid >> 2, c = tid & 3;
    #pragma unroll
    for (int i = 0; i < 2; ++i) {
        int row = r0 + i * 128;
        int cs = c ^ (row & 3);
        gload_lds16(&g[(size_t)row * ldg + cs * 8], &dst[row * 32 + c * 8]);
    }
}

__device__ __forceinline__ void gemm256_core(const unsigned short* A, int ldA,
                                             const unsigned short* Bm, int ldB,
                                             unsigned short* sm, int nt,
                                             f32x4 (&acc)[8][4]) {
    const int tid = threadIdx.x;
    const int w = tid >> 6, l = tid & 63;
    const int lr = l & 15, lg = l >> 4;
    const int wm = (w >> 2) * 128, wn = (w & 3) * 64;
    unsigned short* Asm = sm;               // bytes [0,32768)
    unsigned short* Bsm = sm + 2 * 8192;    // bytes [32768,65536)

    stage256b(A, ldA, Asm, tid);
    stage256b(Bm, ldB, Bsm, tid);
    __syncthreads();

    for (int t = 0; t < nt; ++t) {
        const int cur = (t & 1) * 8192;
        if (t + 1 < nt) {
            const int nxt = ((t + 1) & 1) * 8192;
            stage256b(A  + (size_t)(t + 1) * 32, ldA, Asm + nxt, tid);
            stage256b(Bm + (size_t)(t + 1) * 32, ldB, Bsm + nxt, tid);
        }
        s16x8 av[8], bv[4];
        #pragma unroll
        for (int i = 0; i < 8; ++i) {
            int row = wm + i * 16 + lr;
            av[i] = *(const s16x8*)&Asm[cur + row * 32 + ((lg ^ (row & 3)) * 8)];
        }
        #pragma unroll
        for (int j = 0; j < 4; ++j) {
            int row = wn + j * 16 + lr;
            bv[j] = *(const s16x8*)&Bsm[cur + row * 32 + ((lg ^ (row & 3)) * 8)];
        }
        #pragma unroll
        for (int i = 0; i < 8; ++i)
            #pragma unroll
            for (int j = 0; j < 4; ++j)
                acc[i][j] = __builtin_amdgcn_mfma_f32_16x16x32_bf16(av[i], bv[j], acc[i][j], 0, 0, 0);
        __syncthreads();
    }
}

// ---------------------------------------------------------------- kernel 6: S-GEMM 256^2, 64 KB LDS
// Epilogue transposes in TWO 128-row halves aliased into the (dead) staging
// region: El = [128][256] shorts = 64 KB exactly. smem total 64 KB -> 2 blk/CU.
__global__ __launch_bounds__(512) void sgemm256_k(const unsigned short* __restrict__ q_t,
                                                  const unsigned short* __restrict__ k_t,
                                                  unsigned short* __restrict__ Ptil,
                                                  float* __restrict__ L,
                                                  int bbase) {
    __shared__ char smem[65536];
    int z = blockIdx.z;
    int b = bbase + z;
    int m0 = blockIdx.y * 256, n0 = blockIdx.x * 256;
    const unsigned short* A  = q_t + (size_t)b * N_ * C_ + (size_t)m0 * C_;
    const unsigned short* Bm = k_t + (size_t)b * N_ * C_ + (size_t)n0 * C_;

    f32x4 acc[8][4] = {};
    gemm256_core(A, C_, Bm, C_, (unsigned short*)smem, C_ / 32, acc);
    // core's final __syncthreads: staging buffers now dead -> reuse as El.

    const int tid = threadIdx.x;
    const int w = tid >> 6, l = tid & 63;
    const int lr = l & 15, lg = l >> 4;
    const int mh = w >> 2;                  // which 128-row half this wave owns
    const int wm = mh * 128, wn = (w & 3) * 64;
    const float SCL2 = 0.06375862f;  // log2(e)/sqrt(512)

    unsigned short* El = (unsigned short*)smem;   // [128][256] per half
    unsigned short* Cm = Ptil + (size_t)z * N_ * N_;
    float rsum[8][4];
    #pragma unroll
    for (int i = 0; i < 8; ++i)
        #pragma unroll
        for (int r = 0; r < 4; ++r) rsum[i][r] = 0.f;

    #pragma unroll
    for (int h = 0; h < 2; ++h) {
        if (mh == h) {                       // wave-uniform branch
            #pragma unroll
            for (int i = 0; i < 8; ++i)
                #pragma unroll
                for (int j = 0; j < 4; ++j) {
                    int col = wn + j * 16 + lr;
                    #pragma unroll
                    for (int r = 0; r < 4; ++r) {
                        float p = exp2f(acc[i][j][r] * SCL2);
                        rsum[i][r] += p;
                        El[(i * 16 + lg * 4 + r) * 256 + col] = f2bf(p);
                    }
                }
        }
        __syncthreads();
        #pragma unroll
        for (int it = 0; it < 8; ++it) {
            int u = tid + it * 512;
            int row = u >> 5, part = u & 31;
            *(s16x8*)&Cm[(size_t)(m0 + h * 128 + row) * N_ + n0 + part * 8] =
                *(const s16x8*)&El[row * 256 + part * 8];
        }
        __syncthreads();
    }

    #pragma unroll
    for (int msk = 8; msk >= 1; msk >>= 1)
        #pragma unroll
        for (int i = 0; i < 8; ++i)
            #pragma unroll
            for (int r = 0; r < 4; ++r)
                rsum[i][r] += __shfl_xor(rsum[i][r], msk);
    if (lr == 0) {
        #pragma unroll
        for (int i = 0; i < 8; ++i)
            #pragma unroll
            for (int r = 0; r < 4; ++r)
                atomicAdd(&L[(size_t)b * N_ + m0 + wm + i * 16 + lg * 4 + r], rsum[i][r]);
    }
}

// ---------------------------------------------------------------- kernel 7: PV 128^2
// ATOMIC=false (slots>=4): full K, out = x + acc/L, grid z = slots.
// ATOMIC=true  (slots==2): K split SK ways, out preset to x, grid z = slots*SK.
template <bool ATOMIC>
__global__ __launch_bounds__(256, 4) void pv_k(const unsigned short* __restrict__ vv,
                                               const unsigned short* __restrict__ Ptil,
                                               const float* __restrict__ L,
                                               const float* __restrict__ x,
                                               float* __restrict__ out,
                                               int bbase, int SK) {
    int z = blockIdx.z;
    int slot = z / SK, kr = z % SK;
    int b = bbase + slot;
    int kOff = kr * (N_ / SK);
    const unsigned short* A  = vv + (size_t)b * C_ * N_ + kOff;        // [c][j]
    const unsigned short* Bm = Ptil + (size_t)slot * N_ * N_ + kOff;   // [i][j]
    int m0 = blockIdx.y * 128, n0 = blockIdx.x * 128;
    const float* xb = x + (size_t)b * C_ * N_;
    float* ob = out + (size_t)b * C_ * N_;

    __shared__ char smem[32768];
    unsigned short* Al = (unsigned short*)smem;
    unsigned short* Bl = Al + 8192;

    int t = threadIdx.x;
    int wid = t >> 6, lane = t & 63;
    int wm = (wid >> 1) * 64, wn = (wid & 1) * 64;
    int lr = lane & 15, lg = lane >> 4;

    f32x4 acc[4][4] = {};
    gemm_core(A + (size_t)m0 * N_, N_, Bm + (size_t)n0 * N_, N_, Al, Bl, acc, (N_ / SK) / 32, t);

    #pragma unroll
    for (int j = 0; j < 4; ++j) {
        int col = n0 + wn + j * 16 + lr;
        float rl = 1.0f / L[(size_t)b * N_ + col];
        #pragma unroll
        for (int i = 0; i < 4; ++i) {
            #pragma unroll
            for (int r = 0; r < 4; ++r) {
                int row = m0 + wm + i * 16 + lg * 4 + r;
                size_t off = (size_t)row * N_ + col;
                if (ATOMIC) atomicAdd(&ob[off], acc[i][j][r] * rl);
                else        ob[off] = xb[off] + acc[i][j][r] * rl;
            }
        }
    }
}

// ---------------------------------------------------------------- launch
extern "C" void kernel_launch(void* const* d_in, const int* in_sizes, int n_in,
                              void* d_out, int out_size, void* d_ws, size_t ws_size,
                              hipStream_t stream) {
    const float* x   = (const float*)d_in[0];
    const float* gsc = (const float*)d_in[1];
    const float* gbi = (const float*)d_in[2];
    const float* wq  = (const float*)d_in[3];
    const float* bq  = (const float*)d_in[4];
    const float* wk  = (const float*)d_in[5];
    const float* bk  = (const float*)d_in[6];
    const float* wv  = (const float*)d_in[7];
    const float* bv  = (const float*)d_in[8];
    float* out = (float*)d_out;

    const size_t elems = (size_t)B_ * N_ * C_;   // 16.7M
    unsigned short* q_t   = (unsigned short*)d_ws;
    unsigned short* k_t   = q_t + elems;
    unsigned short* v     = k_t + elems;
    float*          stats = (float*)(v + elems);
    unsigned short* wbf   = (unsigned short*)(stats + 2 * B_ * G_);
    float*          L     = (float*)(wbf + (size_t)3 * C_ * C_);
    unsigned short* Ptil  = (unsigned short*)(L + (size_t)B_ * N_);
    unsigned short* h_t   = (unsigned short*)d_out;  // dead after qkv_k

    const size_t base_bytes = (size_t)((char*)Ptil - (char*)d_ws);
    const size_t slot_bytes = (size_t)N_ * N_ * 2;
    int slots = 2;
    if      (ws_size >= base_bytes + 8 * slot_bytes) slots = 8;
    else if (ws_size >= base_bytes + 4 * slot_bytes) slots = 4;

    gn_stats_k<<<B_ * G_, 256, 0, stream>>>(x, stats);
    cvt_w_k<<<(3 * C_ * C_ / 4) / 256, 256, 0, stream>>>(wq, wk, wv, wbf);
    gn_apply_k<<<dim3(N_ / 64, C_ / 64, B_), 256, 0, stream>>>(x, stats, gsc, gbi, h_t);
    qkv_k<<<dim3(32, 4, 3 * B_), 256, 0, stream>>>(h_t, wbf, bq, bk, bv, q_t, k_t, v);
    zeroL_k<<<(B_ * N_) / 512, 512, 0, stream>>>(L);

    if (slots >= 4) {
        // full-K non-atomic pv: grid z = slots (512+ blocks, 2+ blk/CU), no copyx
        for (int bb = 0; bb < B_; bb += slots) {
            sgemm256_k<<<dim3(16, 16, slots), 512, 0, stream>>>(q_t, k_t, Ptil, L, bb);
            pv_k<false><<<dim3(32, 4, slots), 256, 0, stream>>>(v, Ptil, L, x, out, bb, 1);
        }
    } else {
        copyx_k<<<2048, 256, 0, stream>>>(x, out);   // out = x; pv atomically adds
        for (int bb = 0; bb < B_; bb += 2) {
            sgemm256_k<<<dim3(16, 16, 2), 512, 0, stream>>>(q_t, k_t, Ptil, L, bb);
            pv_k<true><<<dim3(32, 4, 4), 256, 0, stream>>>(v, Ptil, L, x, out, bb, 2);
        }
    }
}

// Round 13
// 637.508 us; speedup vs baseline: 1.4188x; 1.0705x over previous
//
#include <hip/hip_runtime.h>
#include <hip/hip_bf16.h>

#define B_   8
#define C_   512
#define N_   4096
#define G_   32
#define CPG  16
#define EPSV 1e-6f

typedef short s16x8 __attribute__((ext_vector_type(8)));
typedef float f32x4 __attribute__((ext_vector_type(4)));

__device__ __forceinline__ unsigned short f2bf(float f) {
    unsigned u = __builtin_bit_cast(unsigned, f);
    u += 0x7fffu + ((u >> 16) & 1u);
    return (unsigned short)(u >> 16);
}

__device__ __forceinline__ void gload_lds16(const unsigned short* g, unsigned short* l) {
    __builtin_amdgcn_global_load_lds((const __attribute__((address_space(1))) void*)g,
                                     (__attribute__((address_space(3))) void*)l, 16, 0, 0);
}

// ---------------------------------------------------------------- kernel 1
__global__ __launch_bounds__(256) void gn_stats_k(const float* __restrict__ x,
                                                  float* __restrict__ stats) {
    int blk = blockIdx.x;  // b*32+g
    const float4* p = (const float4*)(x + (size_t)blk * (CPG * N_));
    float s = 0.f, ss = 0.f;
    for (int i = threadIdx.x; i < (CPG * N_) / 4; i += 256) {
        float4 v = p[i];
        s  += v.x + v.y + v.z + v.w;
        ss += v.x * v.x + v.y * v.y + v.z * v.z + v.w * v.w;
    }
    for (int off = 32; off > 0; off >>= 1) {
        s  += __shfl_down(s, off);
        ss += __shfl_down(ss, off);
    }
    __shared__ float r0[4], r1[4];
    int wid = threadIdx.x >> 6;
    if ((threadIdx.x & 63) == 0) { r0[wid] = s; r1[wid] = ss; }
    __syncthreads();
    if (threadIdx.x == 0) {
        s  = r0[0] + r0[1] + r0[2] + r0[3];
        ss = r1[0] + r1[1] + r1[2] + r1[3];
        const float inv = 1.0f / (CPG * N_);
        float mean = s * inv;
        float var  = ss * inv - mean * mean;
        stats[2 * blk]     = mean;
        stats[2 * blk + 1] = rsqrtf(var + EPSV);
    }
}

// ---------------------------------------------------------------- kernel 2
__global__ __launch_bounds__(256) void cvt_w_k(const float* __restrict__ wq,
                                               const float* __restrict__ wk,
                                               const float* __restrict__ wv,
                                               unsigned short* __restrict__ wbf) {
    int i = blockIdx.x * 256 + threadIdx.x;
    const int percc = C_ * C_ / 4;
    const float* src; int li;
    if (i < percc)            { src = wq; li = i; }
    else if (i < 2 * percc)   { src = wk; li = i - percc; }
    else                      { src = wv; li = i - 2 * percc; }
    float4 v = ((const float4*)src)[li];
    unsigned u0 = (unsigned)f2bf(v.x) | ((unsigned)f2bf(v.y) << 16);
    unsigned u1 = (unsigned)f2bf(v.z) | ((unsigned)f2bf(v.w) << 16);
    uint2 o; o.x = u0; o.y = u1;
    *(uint2*)&wbf[(size_t)i * 4] = o;
}

// ---------------------------------------------------------------- kernel 3
__global__ __launch_bounds__(256) void gn_apply_k(const float* __restrict__ x,
                                                  const float* __restrict__ stats,
                                                  const float* __restrict__ gsc,
                                                  const float* __restrict__ gbi,
                                                  unsigned short* __restrict__ h_t) {
    int nt = blockIdx.x, ct = blockIdx.y, b = blockIdx.z;
    int n0 = nt * 64, c0 = ct * 64;
    __shared__ unsigned short T[64][72];
    int t = threadIdx.x;
    int cl = t >> 2, ch = t & 3;
    int c = c0 + cl;
    int g = c >> 4;
    float mean = stats[(b * G_ + g) * 2];
    float rstd = stats[(b * G_ + g) * 2 + 1];
    float sc = gsc[c] * rstd;
    float bi = gbi[c] - mean * sc;
    const float* xr = x + (size_t)(b * C_ + c) * N_ + n0 + ch * 16;
    #pragma unroll
    for (int q = 0; q < 4; ++q) {
        float4 v = *(const float4*)(xr + q * 4);
        int nl = ch * 16 + q * 4;
        T[nl + 0][cl] = f2bf(fmaf(v.x, sc, bi));
        T[nl + 1][cl] = f2bf(fmaf(v.y, sc, bi));
        T[nl + 2][cl] = f2bf(fmaf(v.z, sc, bi));
        T[nl + 3][cl] = f2bf(fmaf(v.w, sc, bi));
    }
    __syncthreads();
    #pragma unroll
    for (int it = 0; it < 2; ++it) {
        int id = t + it * 256;
        int nl = id >> 3, part = id & 7;
        s16x8 val = *(const s16x8*)&T[nl][part * 8];
        *(s16x8*)&h_t[((size_t)b * N_ + n0 + nl) * C_ + c0 + part * 8] = val;
    }
}

// ---------------------------------------------------------------- kernel 3b: ranged out=x copy
__global__ __launch_bounds__(256) void copyx_r(const float* __restrict__ x,
                                               float* __restrict__ out,
                                               int bbase, int nb) {
    const size_t per = (size_t)C_ * N_ / 4;
    const size_t off = (size_t)bbase * per;
    const size_t total4 = (size_t)nb * per;
    size_t stride = (size_t)gridDim.x * 256;
    for (size_t i = blockIdx.x * 256 + threadIdx.x; i < total4; i += stride)
        ((float4*)out)[off + i] = ((const float4*)x)[off + i];
}

// ---------------------------------------------------------------- 128^2 2-phase core (proven R5)
__device__ __forceinline__ void gemm_core(const unsigned short* A, int ldA,
                                          const unsigned short* Bm, int ldB,
                                          unsigned short* Al, unsigned short* Bl,
                                          f32x4 (&acc)[4][4], int ksteps, int t) {
    int w = t >> 6, l = t & 63;
    int wm = (w >> 1) * 64, wn = (w & 1) * 64;
    int lr = l & 15, lg = l >> 4;
    int srow = w * 16 + (l >> 2);
    int sp   = (l & 3) * 8;

    #pragma unroll
    for (int it = 0; it < 2; ++it) {
        gload_lds16(&A [(size_t)(it * 64 + srow) * ldA + sp], &Al[it * 2048 + w * 512 + l * 8]);
        gload_lds16(&Bm[(size_t)(it * 64 + srow) * ldB + sp], &Bl[it * 2048 + w * 512 + l * 8]);
    }
    __syncthreads();

    int cur = 0;
    for (int s = 0; s < ksteps; ++s) {
        if (s + 1 < ksteps) {
            const unsigned short* ga = A  + (s + 1) * 32;
            const unsigned short* gb = Bm + (s + 1) * 32;
            int off = (cur ^ 1) * 4096;
            #pragma unroll
            for (int it = 0; it < 2; ++it) {
                gload_lds16(&ga[(size_t)(it * 64 + srow) * ldA + sp], &Al[off + it * 2048 + w * 512 + l * 8]);
                gload_lds16(&gb[(size_t)(it * 64 + srow) * ldB + sp], &Bl[off + it * 2048 + w * 512 + l * 8]);
            }
        }
        const unsigned short* la = Al + cur * 4096;
        const unsigned short* lb = Bl + cur * 4096;
        s16x8 a[4], b[4];
        #pragma unroll
        for (int i = 0; i < 4; ++i) a[i] = *(const s16x8*)&la[(wm + i * 16 + lr) * 32 + lg * 8];
        #pragma unroll
        for (int j = 0; j < 4; ++j) b[j] = *(const s16x8*)&lb[(wn + j * 16 + lr) * 32 + lg * 8];
        #pragma unroll
        for (int i = 0; i < 4; ++i)
            #pragma unroll
            for (int j = 0; j < 4; ++j)
                acc[i][j] = __builtin_amdgcn_mfma_f32_16x16x32_bf16(a[i], b[j], acc[i][j], 0, 0, 0);
        __syncthreads();
        cur ^= 1;
    }
}

// ---------------------------------------------------------------- kernel 4: QKV projections
__global__ __launch_bounds__(256, 4) void qkv_k(const unsigned short* __restrict__ h_t,
                                                const unsigned short* __restrict__ wbf,
                                                const float* __restrict__ bq,
                                                const float* __restrict__ bk,
                                                const float* __restrict__ bv,
                                                unsigned short* __restrict__ q_t,
                                                unsigned short* __restrict__ k_t,
                                                unsigned short* __restrict__ vv) {
    int which = blockIdx.z % 3;
    int b     = blockIdx.z / 3;
    int bx = blockIdx.x, by = blockIdx.y;
    const unsigned short* A;
    const unsigned short* Bm;
    unsigned short* Cm;
    const float* bias;
    int m0, n0; size_t ldc; bool biasRow;
    const unsigned short* hb = h_t + (size_t)b * N_ * C_;
    if (which < 2) {
        A = hb; Bm = wbf + (size_t)which * C_ * C_;
        Cm = (which == 0 ? q_t : k_t) + (size_t)b * N_ * C_;
        bias = (which == 0 ? bq : bk);
        m0 = bx * 128; n0 = by * 128; ldc = C_; biasRow = false;
    } else {
        A = wbf + (size_t)2 * C_ * C_; Bm = hb;
        Cm = vv + (size_t)b * C_ * N_;
        bias = bv;
        m0 = by * 128; n0 = bx * 128; ldc = N_; biasRow = true;
    }

    __shared__ char smem[35072];
    unsigned short* Al = (unsigned short*)smem;
    unsigned short* Bl = Al + 8192;
    unsigned short* El = (unsigned short*)smem;

    int t = threadIdx.x;
    int wid = t >> 6, lane = t & 63;
    int wm = (wid >> 1) * 64, wn = (wid & 1) * 64;
    int lr = lane & 15, lg = lane >> 4;

    f32x4 acc[4][4] = {};
    gemm_core(A + (size_t)m0 * C_, C_, Bm + (size_t)n0 * C_, C_, Al, Bl, acc, C_ / 32, t);

    float rb[4][4], cb[4];
    #pragma unroll
    for (int i = 0; i < 4; ++i)
        #pragma unroll
        for (int r = 0; r < 4; ++r)
            rb[i][r] = biasRow ? bias[m0 + wm + i * 16 + lg * 4 + r] : 0.f;
    #pragma unroll
    for (int j = 0; j < 4; ++j)
        cb[j] = biasRow ? 0.f : bias[n0 + wn + j * 16 + lr];

    #pragma unroll
    for (int i = 0; i < 4; ++i)
        #pragma unroll
        for (int j = 0; j < 4; ++j) {
            int col = wn + j * 16 + lr;
            #pragma unroll
            for (int r = 0; r < 4; ++r) {
                int row = wm + i * 16 + lg * 4 + r;
                El[row * 136 + col] = f2bf(acc[i][j][r] + rb[i][r] + cb[j]);
            }
        }
    __syncthreads();
    #pragma unroll
    for (int it = 0; it < 8; ++it) {
        int id = t + it * 256;
        int row = id >> 4, part = id & 15;
        *(s16x8*)&Cm[(size_t)(m0 + row) * ldc + n0 + part * 8] =
            *(const s16x8*)&El[row * 136 + part * 8];
    }
}

// ---------------------------------------------------------------- kernel 5
__global__ __launch_bounds__(512) void zeroL_k(float* __restrict__ L) {
    L[blockIdx.x * 512 + threadIdx.x] = 0.f;
}

// ---------------------------------------------------------------- kernel 6: S-GEMM 128^2 (proven R5)
__global__ __launch_bounds__(256, 4) void sgemm_k(const unsigned short* __restrict__ q_t,
                                                  const unsigned short* __restrict__ k_t,
                                                  unsigned short* __restrict__ Ptil,
                                                  float* __restrict__ L,
                                                  int bbase) {
    int z = blockIdx.z;
    int b = bbase + z;
    const unsigned short* A  = q_t + (size_t)b * N_ * C_;
    const unsigned short* Bm = k_t + (size_t)b * N_ * C_;
    unsigned short* Cm = Ptil + (size_t)z * N_ * N_;
    int m0 = blockIdx.y * 128, n0 = blockIdx.x * 128;

    __shared__ char smem[35072];
    unsigned short* Al = (unsigned short*)smem;
    unsigned short* Bl = Al + 8192;
    unsigned short* El = (unsigned short*)smem;

    int t = threadIdx.x;
    int wid = t >> 6, lane = t & 63;
    int wm = (wid >> 1) * 64, wn = (wid & 1) * 64;
    int lr = lane & 15, lg = lane >> 4;

    f32x4 acc[4][4] = {};
    gemm_core(A + (size_t)m0 * C_, C_, Bm + (size_t)n0 * C_, C_, Al, Bl, acc, C_ / 32, t);

    const float SCL2 = 0.06375862f;  // log2(e) / sqrt(512)
    float rsum[4][4];
    #pragma unroll
    for (int i = 0; i < 4; ++i)
        #pragma unroll
        for (int r = 0; r < 4; ++r) rsum[i][r] = 0.f;

    #pragma unroll
    for (int i = 0; i < 4; ++i)
        #pragma unroll
        for (int j = 0; j < 4; ++j) {
            int col = wn + j * 16 + lr;
            #pragma unroll
            for (int r = 0; r < 4; ++r) {
                float p = exp2f(acc[i][j][r] * SCL2);
                rsum[i][r] += p;
                El[(wm + i * 16 + lg * 4 + r) * 136 + col] = f2bf(p);
            }
        }
    #pragma unroll
    for (int msk = 8; msk >= 1; msk >>= 1)
        #pragma unroll
        for (int i = 0; i < 4; ++i)
            #pragma unroll
            for (int r = 0; r < 4; ++r)
                rsum[i][r] += __shfl_xor(rsum[i][r], msk);
    if (lr == 0) {
        #pragma unroll
        for (int i = 0; i < 4; ++i)
            #pragma unroll
            for (int r = 0; r < 4; ++r)
                atomicAdd(&L[(size_t)b * N_ + m0 + wm + i * 16 + lg * 4 + r], rsum[i][r]);
    }
    __syncthreads();
    #pragma unroll
    for (int it = 0; it < 8; ++it) {
        int id = t + it * 256;
        int row = id >> 4, part = id & 15;
        *(s16x8*)&Cm[(size_t)(m0 + row) * N_ + n0 + part * 8] =
            *(const s16x8*)&El[row * 136 + part * 8];
    }
}

// ---------------------------------------------------------------- kernel 7: PV 128^2 (proven R5)
// ATOMIC=false: full K (SK=1), out = x + acc/L.
// ATOMIC=true : out preset to x (copyx_r), K split SK ways, atomic adds.
template <bool ATOMIC>
__global__ __launch_bounds__(256, 4) void pv_k(const unsigned short* __restrict__ vv,
                                               const unsigned short* __restrict__ Ptil,
                                               const float* __restrict__ L,
                                               const float* __restrict__ x,
                                               float* __restrict__ out,
                                               int bbase, int SK) {
    int z = blockIdx.z;
    int slot = z / SK, kr = z % SK;
    int b = bbase + slot;
    int kOff = kr * (N_ / SK);
    const unsigned short* A  = vv + (size_t)b * C_ * N_ + kOff;        // [c][j]
    const unsigned short* Bm = Ptil + (size_t)slot * N_ * N_ + kOff;   // [i][j]
    int m0 = blockIdx.y * 128, n0 = blockIdx.x * 128;
    const float* xb = x + (size_t)b * C_ * N_;
    float* ob = out + (size_t)b * C_ * N_;

    __shared__ char smem[32768];
    unsigned short* Al = (unsigned short*)smem;
    unsigned short* Bl = Al + 8192;

    int t = threadIdx.x;
    int wid = t >> 6, lane = t & 63;
    int wm = (wid >> 1) * 64, wn = (wid & 1) * 64;
    int lr = lane & 15, lg = lane >> 4;

    f32x4 acc[4][4] = {};
    gemm_core(A + (size_t)m0 * N_, N_, Bm + (size_t)n0 * N_, N_, Al, Bl, acc, (N_ / SK) / 32, t);

    #pragma unroll
    for (int j = 0; j < 4; ++j) {
        int col = n0 + wn + j * 16 + lr;
        float rl = 1.0f / L[(size_t)b * N_ + col];
        #pragma unroll
        for (int i = 0; i < 4; ++i) {
            #pragma unroll
            for (int r = 0; r < 4; ++r) {
                int row = m0 + wm + i * 16 + lg * 4 + r;
                size_t off = (size_t)row * N_ + col;
                if (ATOMIC) atomicAdd(&ob[off], acc[i][j][r] * rl);
                else        ob[off] = xb[off] + acc[i][j][r] * rl;
            }
        }
    }
}

// ---------------------------------------------------------------- launch
// Buffer plan: d_out (67.1 MB) = h_t [0,33.5M) | q_t [33.5M,67.1M).
//   h_t dead after qkv_k. q_t[bb..] dead after sgemm of its round; pv of round
//   bb writes out[bb..bb+slots) only, which never overlaps a LIVE q_t range
//   (out[0..3] = h_t region; out[4..7] = q_t region, written only after
//   sgemm(4..7) has consumed q_t). ws base shrinks to ~69 MB -> slots=8 needs
//   only ~337 MB of workspace.
extern "C" void kernel_launch(void* const* d_in, const int* in_sizes, int n_in,
                              void* d_out, int out_size, void* d_ws, size_t ws_size,
                              hipStream_t stream) {
    const float* x   = (const float*)d_in[0];
    const float* gsc = (const float*)d_in[1];
    const float* gbi = (const float*)d_in[2];
    const float* wq  = (const float*)d_in[3];
    const float* bq  = (const float*)d_in[4];
    const float* wk  = (const float*)d_in[5];
    const float* bk  = (const float*)d_in[6];
    const float* wv  = (const float*)d_in[7];
    const float* bv  = (const float*)d_in[8];
    float* out = (float*)d_out;

    const size_t elems = (size_t)B_ * N_ * C_;   // 16.7M
    unsigned short* h_t   = (unsigned short*)d_out;          // [0, 33.5M)
    unsigned short* q_t   = h_t + elems;                     // [33.5M, 67.1M)
    unsigned short* k_t   = (unsigned short*)d_ws;
    unsigned short* v     = k_t + elems;
    float*          stats = (float*)(v + elems);
    unsigned short* wbf   = (unsigned short*)(stats + 2 * B_ * G_);
    float*          L     = (float*)(wbf + (size_t)3 * C_ * C_);
    unsigned short* Ptil  = (unsigned short*)(L + (size_t)B_ * N_);

    const size_t base_bytes = (size_t)((char*)Ptil - (char*)d_ws);  // ~69 MB
    const size_t slot_bytes = (size_t)N_ * N_ * 2;                  // 33.55 MB
    int slots = 2;
    if      (ws_size >= base_bytes + 8 * slot_bytes) slots = 8;
    else if (ws_size >= base_bytes + 4 * slot_bytes) slots = 4;

    gn_stats_k<<<B_ * G_, 256, 0, stream>>>(x, stats);
    cvt_w_k<<<(3 * C_ * C_ / 4) / 256, 256, 0, stream>>>(wq, wk, wv, wbf);
    gn_apply_k<<<dim3(N_ / 64, C_ / 64, B_), 256, 0, stream>>>(x, stats, gsc, gbi, h_t);
    qkv_k<<<dim3(32, 4, 3 * B_), 256, 0, stream>>>(h_t, wbf, bq, bk, bv, q_t, k_t, v);
    zeroL_k<<<(B_ * N_) / 512, 512, 0, stream>>>(L);

    if (slots == 8) {
        // single round: no copyx, no atomics, no serialization chain
        sgemm_k<<<dim3(32, 32, 8), 256, 0, stream>>>(q_t, k_t, Ptil, L, 0);
        pv_k<false><<<dim3(32, 4, 8), 256, 0, stream>>>(v, Ptil, L, x, out, 0, 1);
    } else {
        const int SK = 8 / slots;   // pv z = slots*SK = 8 always (1024 blocks)
        for (int bb = 0; bb < B_; bb += slots) {
            sgemm_k<<<dim3(32, 32, slots), 256, 0, stream>>>(q_t, k_t, Ptil, L, bb);
            // copyx AFTER sgemm(bb): it may overwrite q_t ranges already consumed
            copyx_r<<<1024, 256, 0, stream>>>(x, out, bb, slots);
            pv_k<true><<<dim3(32, 4, 8), 256, 0, stream>>>(v, Ptil, L, x, out, bb, SK);
        }
    }
}